// Round 10
// baseline (206.504 us; speedup 1.0000x reference)
//
#include <hip/hip_runtime.h>
#include <hip/hip_bf16.h>

#define BATCH   16384
#define NSTEPS  100
#define DT_     0.01f
#define SQRTDT  0.1f
#define SIGMA0_ 0.5f

typedef short     bf16x8 __attribute__((ext_vector_type(8)));
typedef __fp16    h16x2  __attribute__((ext_vector_type(2)));
typedef _Float16  f16x4  __attribute__((ext_vector_type(4)));
typedef float     f32x2  __attribute__((ext_vector_type(2)));
typedef float     f32x4  __attribute__((ext_vector_type(4)));

__global__ void zero_out_kernel(float* out) { if (threadIdx.x == 0) out[0] = 0.0f; }

static __device__ __forceinline__ unsigned packbf16(float a, float b) {
    union { __hip_bfloat162 h; unsigned u; } cv;
    cv.h = __float22bfloat162_rn(make_float2(a, b));
    return cv.u;
}
static __device__ __forceinline__ unsigned short bf16bits(float x) {
    union { __hip_bfloat16 h; unsigned short u; } cv;
    cv.h = __float2bfloat16(x);
    return cv.u;
}
// pack 4 floats -> f16x4 via two v_cvt_pkrtz_f16_f32
static __device__ __forceinline__ f16x4 pk4(const f32x4& d) {
    union { h16x2 h[2]; f16x4 v; } c;
    c.h[0] = __builtin_amdgcn_cvt_pkrtz(d[0], d[1]);
    c.h[1] = __builtin_amdgcn_cvt_pkrtz(d[2], d[3]);
    return c.v;
}

// One wave = 16 paths, BOTH MLPs, no LDS, no barriers, 1024 free-running
// waves (256 blk x 256 thr). Diet vs R8: pk-f32 h1, pkrtz f16 conversion,
// single y-broadcast (epilogue runs on all lanes, valid on q4==0), layer-3
// as 4 independent 2-deep MFMA chains.
__launch_bounds__(256, 1)
__global__ void deepbsde_kernel(
    const float* __restrict__ y0,  const float* __restrict__ Y0,
    const float* __restrict__ zW1, const float* __restrict__ zb1,
    const float* __restrict__ zW2, const float* __restrict__ zb2,
    const float* __restrict__ zW3, const float* __restrict__ zb3,
    const float* __restrict__ qW1, const float* __restrict__ qb1,
    const float* __restrict__ qW2, const float* __restrict__ qb2,
    const float* __restrict__ qW3, const float* __restrict__ qb3,
    const float* __restrict__ dW,  const float* __restrict__ dZ,
    float* __restrict__ out)
{
    const int tid  = threadIdx.x;
    const int lane = tid & 63;
    const int w    = tid >> 6;
    const int ln15 = lane & 15, q4 = lane >> 4;
    const int gw   = (blockIdx.x << 2) + w;
    const int pl   = (gw << 4) + ln15;           // this lane's path

    // layer-1 consts as f32x2 pairs; pair m covers frag idx (2m, 2m+1),
    // k(idx) = 32*(idx>>3) + 8*q4 + (idx&7)
    f32x2 A1z[8], B1z[8], C1z[8], A1q[8], B1q[8], C1q[8];
#pragma unroll
    for (int m = 0; m < 8; ++m) {
        int i0 = 2*m, i1 = 2*m + 1;
        int k0 = 32*(i0 >> 3) + 8*q4 + (i0 & 7);
        int k1 = 32*(i1 >> 3) + 8*q4 + (i1 & 7);
        A1z[m] = (f32x2){zW1[k0],      zW1[k1]};
        B1z[m] = (f32x2){zW1[64 + k0], zW1[64 + k1]};
        C1z[m] = (f32x2){zb1[k0],      zb1[k1]};
        A1q[m] = (f32x2){qW1[k0],      qW1[k1]};
        B1q[m] = (f32x2){qW1[64 + k0], qW1[64 + k1]};
        C1q[m] = (f32x2){qb1[k0],      qb1[k1]};
    }

    // resident W2^T A-frags: A[n=16tN+ln15][k=32f+8q4+j]
    bf16x8 AfZ[4][2], AfQ[4][2];
#pragma unroll
    for (int tN = 0; tN < 4; ++tN)
#pragma unroll
        for (int f = 0; f < 2; ++f)
#pragma unroll
            for (int j = 0; j < 8; ++j) {
                int k = 32*f + 8*q4 + j, n = 16*tN + ln15;
                AfZ[tN][f][j] = (short)bf16bits(zW2[k*64 + n]);
                AfQ[tN][f][j] = (short)bf16bits(qW2[k*64 + n]);
            }

    // layer-2 bias along Dt rows: row n = 16tN + 4q4 + r
    f32x4 b2zv[4], b2qv[4];
#pragma unroll
    for (int tN = 0; tN < 4; ++tN)
#pragma unroll
        for (int r = 0; r < 4; ++r) {
            b2zv[tN][r] = zb2[16*tN + 4*q4 + r];
            b2qv[tN][r] = qb2[16*tN + 4*q4 + r];
        }

    // stacked W3^T A-frags (16x16x16): A[m=ln15][k=16tN+4q4+j]
    f16x4 A3z[4], A3q[4];
#pragma unroll
    for (int tN = 0; tN < 4; ++tN)
#pragma unroll
        for (int j = 0; j < 4; ++j) {
            int n = 16*tN + 4*q4 + j;
            A3z[tN][j] = (_Float16)((ln15 < 3)  ? zW3[n*3 + ln15] : 0.0f);
            A3q[tN][j] = (_Float16)((ln15 == 3) ? qW3[n]          : 0.0f);
        }

    float y = y0[0], Yv = Y0[0], t = 0.0f, acc = 0.0f;
    const float zb30 = zb3[0], zb31 = zb3[1], zb32 = zb3[2], qb30 = qb3[0];

    const size_t STRIDE = (size_t)BATCH * 3;
    const float* pW = dW + (size_t)pl * 3;
    const float* pZ = dZ + (size_t)pl * 3;
    float wa0 = pW[0], wa1 = pW[1], wa2 = pW[2];
    float za0 = pZ[0], za1 = pZ[1], za2 = pZ[2];
    float wb0 = pW[STRIDE], wb1 = pW[STRIDE+1], wb2 = pW[STRIDE+2];
    float vb0 = pZ[STRIDE], vb1 = pZ[STRIDE+1], vb2 = pZ[STRIDE+2];
    pW += 2*STRIDE;  pZ += 2*STRIDE;

    const f32x2 zero2 = {0.0f, 0.0f};
    const f32x4 zero4 = {0.0f, 0.0f, 0.0f, 0.0f};

    auto step = [&](float nw0, float nw1, float nw2,
                    float nz0, float nz1, float nz2) {
        // ---- h1 for both MLPs, packed f32x2 (pk_fma/pk_max) ----
        const f32x2 tv = {t, t}, yv = {y, y};
        union { unsigned u[4]; bf16x8 v; } bz0v, bz1v, bq0v, bq1v;
#pragma unroll
        for (int m = 0; m < 8; ++m) {
            f32x2 hz = __builtin_elementwise_max(B1z[m]*yv + (A1z[m]*tv + C1z[m]), zero2);
            f32x2 hq = __builtin_elementwise_max(B1q[m]*yv + (A1q[m]*tv + C1q[m]), zero2);
            unsigned uz = packbf16(hz[0], hz[1]);
            unsigned uq = packbf16(hq[0], hq[1]);
            if (m < 4) { bz0v.u[m] = uz; bq0v.u[m] = uq; }
            else       { bz1v.u[m-4] = uz; bq1v.u[m-4] = uq; }
        }

        // ---- layer-2: Dt[n][path]; relu (pk_max) -> pkrtz f16 B-frags ----
        f16x4 B3z[4], B3q[4];
#pragma unroll
        for (int tN = 0; tN < 4; ++tN) {
            f32x4 dz = b2zv[tN];
            dz = __builtin_amdgcn_mfma_f32_16x16x32_bf16(AfZ[tN][0], bz0v.v, dz, 0, 0, 0);
            dz = __builtin_amdgcn_mfma_f32_16x16x32_bf16(AfZ[tN][1], bz1v.v, dz, 0, 0, 0);
            f32x4 dq = b2qv[tN];
            dq = __builtin_amdgcn_mfma_f32_16x16x32_bf16(AfQ[tN][0], bq0v.v, dq, 0, 0, 0);
            dq = __builtin_amdgcn_mfma_f32_16x16x32_bf16(AfQ[tN][1], bq1v.v, dq, 0, 0, 0);
            dz = __builtin_elementwise_max(dz, zero4);
            dq = __builtin_elementwise_max(dq, zero4);
            B3z[tN] = pk4(dz);
            B3q[tN] = pk4(dq);
        }

        // ---- layer-3: 4 independent 2-deep chains, pairwise add ----
        f32x4 P0 = zero4, P1 = zero4, P2 = zero4, P3 = zero4;
        P0 = __builtin_amdgcn_mfma_f32_16x16x16f16(A3z[0], B3z[0], P0, 0, 0, 0);
        P1 = __builtin_amdgcn_mfma_f32_16x16x16f16(A3z[1], B3z[1], P1, 0, 0, 0);
        P2 = __builtin_amdgcn_mfma_f32_16x16x16f16(A3z[2], B3z[2], P2, 0, 0, 0);
        P3 = __builtin_amdgcn_mfma_f32_16x16x16f16(A3z[3], B3z[3], P3, 0, 0, 0);
        P0 = __builtin_amdgcn_mfma_f32_16x16x16f16(A3q[0], B3q[0], P0, 0, 0, 0);
        P1 = __builtin_amdgcn_mfma_f32_16x16x16f16(A3q[1], B3q[1], P1, 0, 0, 0);
        P2 = __builtin_amdgcn_mfma_f32_16x16x16f16(A3q[2], B3q[2], P2, 0, 0, 0);
        P3 = __builtin_amdgcn_mfma_f32_16x16x16f16(A3q[3], B3q[3], P3, 0, 0, 0);
        f32x4 P = (P0 + P1) + (P2 + P3);

        // ---- epilogue on ALL lanes (P rows valid on q4==0); broadcast y only ----
        float z0 = P[0] + zb30;
        float z1 = P[1] + zb31;
        float z2 = P[2] + zb32;
        float qv = P[3] + qb30;

        f32x2 n0 = {nw0, nz0}, n1 = {nw1, nz1}, n2 = {nw2, nz2};
        f32x2 s0 = n0 * SQRTDT, s1 = n1 * SQRTDT, s2 = n2 * SQRTDT;
        f32x2 z0v = {z0, z0}, z1v = {z1, z1}, z2v = {z2, z2};
        f32x2 zd = z2v*s2 + (z1v*s1 + z0v*s0);   // (zdw, zdz)
        float zdw = zd[0], zdz = zd[1];
        float f = 0.5f*qv*qv;
        Yv = Yv - f*DT_ + zdw;
        float r = zdw - zdz;                     // residual: (Y - f*DT) cancels
        acc = fmaf(r, r, acc);
        y = y + qv*DT_ + SIGMA0_*(s0[0] + s1[0] + s2[0]);
        y = __shfl(y, ln15);                     // re-validate all q4 replicas
        t += DT_;
    };

#pragma unroll 1
    for (int i = 0; i < NSTEPS; i += 2) {
        step(wa0, wa1, wa2, za0, za1, za2);
        if (i + 2 < NSTEPS) {
            wa0 = pW[0]; wa1 = pW[1]; wa2 = pW[2];
            za0 = pZ[0]; za1 = pZ[1]; za2 = pZ[2];
            pW += STRIDE; pZ += STRIDE;
        }
        step(wb0, wb1, wb2, vb0, vb1, vb2);
        if (i + 3 < NSTEPS) {
            wb0 = pW[0]; wb1 = pW[1]; wb2 = pW[2];
            vb0 = pZ[0]; vb1 = pZ[1]; vb2 = pZ[2];
            pW += STRIDE; pZ += STRIDE;
        }
    }

    float dterm = Yv - y*y;
    acc = fmaf(dterm, dterm, acc);

    // acc valid on q4==0 lanes only; count each path once
    float val = (q4 == 0) ? acc : 0.0f;
#pragma unroll
    for (int off = 1; off < 64; off <<= 1) val += __shfl_xor(val, off);
    if (lane == 0) atomicAdd(out, val * (1.0f / BATCH));
}

extern "C" void kernel_launch(void* const* d_in, const int* in_sizes, int n_in,
                              void* d_out, int out_size, void* d_ws, size_t ws_size,
                              hipStream_t stream)
{
    zero_out_kernel<<<1, 64, 0, stream>>>((float*)d_out);
    deepbsde_kernel<<<256, 256, 0, stream>>>(
        (const float*)d_in[0],  (const float*)d_in[1],
        (const float*)d_in[2],  (const float*)d_in[3],
        (const float*)d_in[4],  (const float*)d_in[5],
        (const float*)d_in[6],  (const float*)d_in[7],
        (const float*)d_in[8],  (const float*)d_in[9],
        (const float*)d_in[10], (const float*)d_in[11],
        (const float*)d_in[12], (const float*)d_in[13],
        (const float*)d_in[14], (const float*)d_in[15],
        (float*)d_out);
}

// Round 11
// 193.752 us; speedup vs baseline: 1.0658x; 1.0658x over previous
//
#include <hip/hip_runtime.h>
#include <hip/hip_bf16.h>

#define BATCH   16384
#define NSTEPS  100
#define DT_     0.01f
#define SQRTDT  0.1f
#define SIGMA0_ 0.5f

typedef short     bf16x8 __attribute__((ext_vector_type(8)));
typedef __fp16    h16x2  __attribute__((ext_vector_type(2)));
typedef _Float16  f16x4  __attribute__((ext_vector_type(4)));
typedef float     f32x2  __attribute__((ext_vector_type(2)));
typedef float     f32x4  __attribute__((ext_vector_type(4)));

__global__ void zero_out_kernel(float* out) { if (threadIdx.x == 0) out[0] = 0.0f; }

static __device__ __forceinline__ unsigned packbf16(float a, float b) {
    union { __hip_bfloat162 h; unsigned u; } cv;
    cv.h = __float22bfloat162_rn(make_float2(a, b));
    return cv.u;
}
static __device__ __forceinline__ unsigned short bf16bits(float x) {
    union { __hip_bfloat16 h; unsigned short u; } cv;
    cv.h = __float2bfloat16(x);
    return cv.u;
}
static __device__ __forceinline__ f16x4 pk4(const f32x4& d) {
    union { h16x2 h[2]; f16x4 v; } c;
    c.h[0] = __builtin_amdgcn_cvt_pkrtz(d[0], d[1]);
    c.h[1] = __builtin_amdgcn_cvt_pkrtz(d[2], d[3]);
    return c.v;
}

// 128-thread blocks: wave 0 = z-MLP, wave 1 = q-MLP, 16 paths/block
// (path = lane&15). 1024 blocks -> 2048 waves = 2/SIMD, and co-resident
// waves on a SIMD come from DIFFERENT blocks -> real latency hiding
// (R4/R8 lesson: same-block lockstep waves don't cover each other).
// Exchange: 256B double-buffered float4[16] (z writes xyz, q writes w),
// ONE barrier/step; all lanes read z&q from LDS so the epilogue is valid
// on every lane and no shfl sits in the serial chain.
__launch_bounds__(128, 2)
__global__ void deepbsde_kernel(
    const float* __restrict__ y0,  const float* __restrict__ Y0,
    const float* __restrict__ zW1, const float* __restrict__ zb1,
    const float* __restrict__ zW2, const float* __restrict__ zb2,
    const float* __restrict__ zW3, const float* __restrict__ zb3,
    const float* __restrict__ qW1, const float* __restrict__ qb1,
    const float* __restrict__ qW2, const float* __restrict__ qb2,
    const float* __restrict__ qW3, const float* __restrict__ qb3,
    const float* __restrict__ dW,  const float* __restrict__ dZ,
    float* __restrict__ out)
{
    __shared__ float4 pout[2][16];   // (z0,z1,z2,q) per path, double-buffered

    const int tid  = threadIdx.x;
    const int lane = tid & 63;
    const int w    = tid >> 6;       // 0 = z-wave, 1 = q-wave
    const int ln15 = lane & 15, q4 = lane >> 4;
    const int pl   = (blockIdx.x << 4) + ln15;   // this lane's path

    const float* __restrict__ W1s = w ? qW1 : zW1;
    const float* __restrict__ b1s = w ? qb1 : zb1;
    const float* __restrict__ W2s = w ? qW2 : zW2;
    const float* __restrict__ b2s = w ? qb2 : zb2;

    // layer-1 consts as f32x2 pairs; pair m covers frag idx (2m,2m+1),
    // k(idx) = 32*(idx>>3) + 8*q4 + (idx&7)
    f32x2 A1[8], B1[8], C1[8];
#pragma unroll
    for (int m = 0; m < 8; ++m) {
        int i0 = 2*m, i1 = 2*m + 1;
        int k0 = 32*(i0 >> 3) + 8*q4 + (i0 & 7);
        int k1 = 32*(i1 >> 3) + 8*q4 + (i1 & 7);
        A1[m] = (f32x2){W1s[k0],      W1s[k1]};
        B1[m] = (f32x2){W1s[64 + k0], W1s[64 + k1]};
        C1[m] = (f32x2){b1s[k0],      b1s[k1]};
    }

    // resident W2^T A-frags: A[n=16tN+ln15][k=32f+8q4+j]  (layout verified R5-R10)
    bf16x8 Af[4][2];
#pragma unroll
    for (int tN = 0; tN < 4; ++tN)
#pragma unroll
        for (int f = 0; f < 2; ++f)
#pragma unroll
            for (int j = 0; j < 8; ++j)
                Af[tN][f][j] = (short)bf16bits(W2s[(32*f + 8*q4 + j)*64 + 16*tN + ln15]);

    // layer-2 bias along Dt rows: row n = 16tN + 4q4 + r
    f32x4 b2v[4];
#pragma unroll
    for (int tN = 0; tN < 4; ++tN)
#pragma unroll
        for (int r = 0; r < 4; ++r) b2v[tN][r] = b2s[16*tN + 4*q4 + r];

    // W3^T A-frags (16x16x16): A[m=ln15][k=16tN+4q4+j]
    // z-wave: rows 0-2 = zW3 columns; q-wave: row 0 = qW3
    f16x4 A3[4];
#pragma unroll
    for (int tN = 0; tN < 4; ++tN)
#pragma unroll
        for (int j = 0; j < 4; ++j) {
            int n = 16*tN + 4*q4 + j;
            float v = w ? (ln15 == 0 ? qW3[n] : 0.0f)
                        : (ln15 < 3  ? zW3[n*3 + ln15] : 0.0f);
            A3[tN][j] = (_Float16)v;
        }

    float y = y0[0], Yv = Y0[0], t = 0.0f, acc = 0.0f;
    const float zb30 = zb3[0], zb31 = zb3[1], zb32 = zb3[2], qb30 = qb3[0];

    const size_t STRIDE = (size_t)BATCH * 3;
    const float* pW = dW + (size_t)pl * 3;
    const float* pZ = dZ + (size_t)pl * 3;
    float wa0 = pW[0], wa1 = pW[1], wa2 = pW[2];
    float za0 = pZ[0], za1 = pZ[1], za2 = pZ[2];
    float wb0 = pW[STRIDE], wb1 = pW[STRIDE+1], wb2 = pW[STRIDE+2];
    float vb0 = pZ[STRIDE], vb1 = pZ[STRIDE+1], vb2 = pZ[STRIDE+2];
    pW += 2*STRIDE;  pZ += 2*STRIDE;

    const f32x2 zero2 = {0.0f, 0.0f};
    const f32x4 zero4 = {0.0f, 0.0f, 0.0f, 0.0f};
    float* pout_f = (float*)&pout[0][0];
    int step_i = 0;

    auto step = [&](float nw0, float nw1, float nw2,
                    float nz0, float nz1, float nz2) {
        // ---- h1 frag (this wave's MLP), packed f32x2 ----
        const f32x2 tv = {t, t}, yv = {y, y};
        union { unsigned u[4]; bf16x8 v; } b0v, b1vv;
#pragma unroll
        for (int m = 0; m < 8; ++m) {
            f32x2 h = __builtin_elementwise_max(B1[m]*yv + (A1[m]*tv + C1[m]), zero2);
            unsigned u = packbf16(h[0], h[1]);
            if (m < 4) b0v.u[m] = u; else b1vv.u[m-4] = u;
        }

        // ---- layer-2: Dt[n][path]; relu -> f16 B-frags ----
        f16x4 B3[4];
#pragma unroll
        for (int tN = 0; tN < 4; ++tN) {
            f32x4 d = b2v[tN];
            d = __builtin_amdgcn_mfma_f32_16x16x32_bf16(Af[tN][0], b0v.v,  d, 0, 0, 0);
            d = __builtin_amdgcn_mfma_f32_16x16x32_bf16(Af[tN][1], b1vv.v, d, 0, 0, 0);
            B3[tN] = pk4(__builtin_elementwise_max(d, zero4));
        }

        // ---- layer-3: 4 independent 1-deep chains, pairwise add ----
        f32x4 P0 = zero4, P1 = zero4, P2 = zero4, P3 = zero4;
        P0 = __builtin_amdgcn_mfma_f32_16x16x16f16(A3[0], B3[0], P0, 0, 0, 0);
        P1 = __builtin_amdgcn_mfma_f32_16x16x16f16(A3[1], B3[1], P1, 0, 0, 0);
        P2 = __builtin_amdgcn_mfma_f32_16x16x16f16(A3[2], B3[2], P2, 0, 0, 0);
        P3 = __builtin_amdgcn_mfma_f32_16x16x16f16(A3[3], B3[3], P3, 0, 0, 0);
        f32x4 P = (P0 + P1) + (P2 + P3);

        // ---- exchange: z writes xyz, q writes w; one barrier ----
        const int buf = step_i & 1;
        float* slot = pout_f + (buf*16 + ln15)*4;
        if (q4 == 0) {
            if (w == 0) { slot[0] = P[0]; slot[1] = P[1]; slot[2] = P[2]; }
            else        { slot[3] = P[0]; }
        }
        __syncthreads();
        float4 zq = pout[buf][ln15];

        // ---- epilogue, valid on ALL lanes (z,q from LDS) ----
        float z0 = zq.x + zb30, z1 = zq.y + zb31, z2 = zq.z + zb32;
        float qv = zq.w + qb30;

        f32x2 n0 = {nw0, nz0}, n1 = {nw1, nz1}, n2 = {nw2, nz2};
        f32x2 s0 = n0 * SQRTDT, s1 = n1 * SQRTDT, s2 = n2 * SQRTDT;
        f32x2 z0v = {z0, z0}, z1v = {z1, z1}, z2v = {z2, z2};
        f32x2 zd = z2v*s2 + (z1v*s1 + z0v*s0);   // (zdw, zdz)
        float zdw = zd[0], zdz = zd[1];
        float f = 0.5f*qv*qv;
        Yv = Yv - f*DT_ + zdw;
        float r = zdw - zdz;                     // residual: (Y - f*DT) cancels
        acc = fmaf(r, r, acc);
        y = y + qv*DT_ + SIGMA0_*(s0[0] + s1[0] + s2[0]);
        t += DT_;
        ++step_i;
    };

#pragma unroll 1
    for (int i = 0; i < NSTEPS; i += 2) {
        step(wa0, wa1, wa2, za0, za1, za2);
        if (i + 2 < NSTEPS) {
            wa0 = pW[0]; wa1 = pW[1]; wa2 = pW[2];
            za0 = pZ[0]; za1 = pZ[1]; za2 = pZ[2];
            pW += STRIDE; pZ += STRIDE;
        }
        step(wb0, wb1, wb2, vb0, vb1, vb2);
        if (i + 3 < NSTEPS) {
            wb0 = pW[0]; wb1 = pW[1]; wb2 = pW[2];
            vb0 = pZ[0]; vb1 = pZ[1]; vb2 = pZ[2];
            pW += STRIDE; pZ += STRIDE;
        }
    }

    float dterm = Yv - y*y;
    acc = fmaf(dterm, dterm, acc);

    // each path counted once: z-wave, q4==0 lanes
    if (w == 0) {
        float val = (q4 == 0) ? acc : 0.0f;
#pragma unroll
        for (int off = 1; off < 64; off <<= 1) val += __shfl_xor(val, off);
        if (lane == 0) atomicAdd(out, val * (1.0f / BATCH));
    }
}

extern "C" void kernel_launch(void* const* d_in, const int* in_sizes, int n_in,
                              void* d_out, int out_size, void* d_ws, size_t ws_size,
                              hipStream_t stream)
{
    zero_out_kernel<<<1, 64, 0, stream>>>((float*)d_out);
    deepbsde_kernel<<<1024, 128, 0, stream>>>(
        (const float*)d_in[0],  (const float*)d_in[1],
        (const float*)d_in[2],  (const float*)d_in[3],
        (const float*)d_in[4],  (const float*)d_in[5],
        (const float*)d_in[6],  (const float*)d_in[7],
        (const float*)d_in[8],  (const float*)d_in[9],
        (const float*)d_in[10], (const float*)d_in[11],
        (const float*)d_in[12], (const float*)d_in[13],
        (const float*)d_in[14], (const float*)d_in[15],
        (float*)d_out);
}

// Round 12
// 188.843 us; speedup vs baseline: 1.0935x; 1.0260x over previous
//
#include <hip/hip_runtime.h>
#include <hip/hip_bf16.h>

#define BATCH   16384
#define NSTEPS  100
#define DT_     0.01f
#define SQRTDT  0.1f
#define SIGMA0_ 0.5f

typedef short     bf16x8 __attribute__((ext_vector_type(8)));
typedef __fp16    h16x2  __attribute__((ext_vector_type(2)));
typedef _Float16  f16x4  __attribute__((ext_vector_type(4)));
typedef float     f32x2  __attribute__((ext_vector_type(2)));
typedef float     f32x4  __attribute__((ext_vector_type(4)));

typedef const __attribute__((address_space(1))) void* gas_ptr;
typedef __attribute__((address_space(3))) void*       las_ptr;

__global__ void zero_out_kernel(float* out) { if (threadIdx.x == 0) out[0] = 0.0f; }

static __device__ __forceinline__ unsigned packbf16(float a, float b) {
    union { __hip_bfloat162 h; unsigned u; } cv;
    cv.h = __float22bfloat162_rn(make_float2(a, b));
    return cv.u;
}
static __device__ __forceinline__ unsigned short bf16bits(float x) {
    union { __hip_bfloat16 h; unsigned short u; } cv;
    cv.h = __float2bfloat16(x);
    return cv.u;
}
static __device__ __forceinline__ f16x4 pk4(const f32x4& d) {
    union { h16x2 h[2]; f16x4 v; } c;
    c.h[0] = __builtin_amdgcn_cvt_pkrtz(d[0], d[1]);
    c.h[1] = __builtin_amdgcn_cvt_pkrtz(d[2], d[3]);
    return c.v;
}

// One wave = 16 paths, both MLPs, no barriers, no cross-lane ops in the loop.
// Noise arrives via an 8-slot LDS ring filled by global_load_lds (1 instr/
// step, depth-4 prefetch) with manual s_waitcnt vmcnt(3) — prefetch distance
// the compiler can't collapse. Layer-3 W3^T rows are REPLICATED across the
// four row-quads, so every lane's P = (z0,z1,z2,q): epilogue fully per-lane.
__launch_bounds__(256, 1)
__global__ void deepbsde_kernel(
    const float* __restrict__ y0,  const float* __restrict__ Y0,
    const float* __restrict__ zW1, const float* __restrict__ zb1,
    const float* __restrict__ zW2, const float* __restrict__ zb2,
    const float* __restrict__ zW3, const float* __restrict__ zb3,
    const float* __restrict__ qW1, const float* __restrict__ qb1,
    const float* __restrict__ qW2, const float* __restrict__ qb2,
    const float* __restrict__ qW3, const float* __restrict__ qb3,
    const float* __restrict__ dW,  const float* __restrict__ dZ,
    float* __restrict__ out)
{
    __shared__ __align__(16) char ring[4][8][384];   // [wave][slot][16 paths * 24B]

    const int tid  = threadIdx.x;
    const int lane = tid & 63;
    const int w    = tid >> 6;
    const int ln15 = lane & 15, q4 = lane >> 4;
    const int gw   = (blockIdx.x << 2) + w;
    const int pbase = gw << 4;

    // ---- layer-1 consts (f32x2 pairs) + running V = A*t + C ----
    f32x2 A1z[8], B1z[8], V1z[8], A1q[8], B1q[8], V1q[8];
#pragma unroll
    for (int m = 0; m < 8; ++m) {
        int i0 = 2*m, i1 = 2*m + 1;
        int k0 = 32*(i0 >> 3) + 8*q4 + (i0 & 7);
        int k1 = 32*(i1 >> 3) + 8*q4 + (i1 & 7);
        A1z[m] = (f32x2){zW1[k0],      zW1[k1]};
        B1z[m] = (f32x2){zW1[64 + k0], zW1[64 + k1]};
        V1z[m] = (f32x2){zb1[k0],      zb1[k1]};      // t = 0
        A1q[m] = (f32x2){qW1[k0],      qW1[k1]};
        B1q[m] = (f32x2){qW1[64 + k0], qW1[64 + k1]};
        V1q[m] = (f32x2){qb1[k0],      qb1[k1]};
    }

    // ---- resident W2^T A-frags: A[n=16tN+ln15][k=32f+8q4+j] ----
    bf16x8 AfZ[4][2], AfQ[4][2];
#pragma unroll
    for (int tN = 0; tN < 4; ++tN)
#pragma unroll
        for (int f = 0; f < 2; ++f)
#pragma unroll
            for (int j = 0; j < 8; ++j) {
                int k = 32*f + 8*q4 + j, n = 16*tN + ln15;
                AfZ[tN][f][j] = (short)bf16bits(zW2[k*64 + n]);
                AfQ[tN][f][j] = (short)bf16bits(qW2[k*64 + n]);
            }

    // ---- layer-2 bias along Dt rows: row n = 16tN + 4q4 + r ----
    f32x4 b2zv[4], b2qv[4];
#pragma unroll
    for (int tN = 0; tN < 4; ++tN)
#pragma unroll
        for (int r = 0; r < 4; ++r) {
            b2zv[tN][r] = zb2[16*tN + 4*q4 + r];
            b2qv[tN][r] = qb2[16*tN + 4*q4 + r];
        }

    // ---- layer-3 W3^T A-frags, rows REPLICATED across row-quads:
    //      row m holds W3 column (m&3)  ->  P[r] valid on every lane ----
    const int c3 = ln15 & 3;
    f16x4 A3z[4], A3q[4];
#pragma unroll
    for (int tN = 0; tN < 4; ++tN)
#pragma unroll
        for (int j = 0; j < 4; ++j) {
            int n = 16*tN + 4*q4 + j;
            A3z[tN][j] = (_Float16)((c3 < 3)  ? zW3[n*3 + c3] : 0.0f);
            A3q[tN][j] = (_Float16)((c3 == 3) ? qW3[n]        : 0.0f);
        }

    float y = y0[0], Yv = Y0[0], acc = 0.0f;
    const float zb30 = zb3[0], zb31 = zb3[1], zb32 = zb3[2], qb30 = qb3[0];

    const f32x2 zero2 = {0.0f, 0.0f};
    const f32x4 zero4 = {0.0f, 0.0f, 0.0f, 0.0f};

    // ---- async noise ring ----
    auto fill = [&](int i) {
        if (lane < 24) {
            const char* g = (lane < 12)
                ? (const char*)dW + ((size_t)i * BATCH + pbase) * 12 + (size_t)lane * 16
                : (const char*)dZ + ((size_t)i * BATCH + pbase) * 12 + (size_t)(lane - 12) * 16;
            __builtin_amdgcn_global_load_lds((gas_ptr)g, (las_ptr)&ring[w][i & 7][0],
                                             16, 0, 0);
        }
    };
    fill(0); fill(1); fill(2); fill(3);

    auto body = [&](int i) {
        // noise from this wave's ring slot (vmcnt already satisfied by caller)
        const float* sl = (const float*)&ring[w][i & 7][0];
        float nw0 = sl[ln15*3 + 0], nw1 = sl[ln15*3 + 1], nw2 = sl[ln15*3 + 2];
        float nz0 = sl[48 + ln15*3 + 0], nz1 = sl[48 + ln15*3 + 1], nz2 = sl[48 + ln15*3 + 2];

        // ---- h1 frags, both MLPs (packed f32x2) ----
        const f32x2 yv = {y, y};
        union { unsigned u[4]; bf16x8 v; } bz0v, bz1v, bq0v, bq1v;
#pragma unroll
        for (int m = 0; m < 8; ++m) {
            f32x2 hz = __builtin_elementwise_max(B1z[m]*yv + V1z[m], zero2);
            f32x2 hq = __builtin_elementwise_max(B1q[m]*yv + V1q[m], zero2);
            unsigned uz = packbf16(hz[0], hz[1]);
            unsigned uq = packbf16(hq[0], hq[1]);
            if (m < 4) { bz0v.u[m] = uz; bq0v.u[m] = uq; }
            else       { bz1v.u[m-4] = uz; bq1v.u[m-4] = uq; }
        }

        // ---- layer-2: Dt[n][path]; relu -> f16 B-frags ----
        f16x4 B3z[4], B3q[4];
#pragma unroll
        for (int tN = 0; tN < 4; ++tN) {
            f32x4 dz = b2zv[tN];
            dz = __builtin_amdgcn_mfma_f32_16x16x32_bf16(AfZ[tN][0], bz0v.v, dz, 0, 0, 0);
            dz = __builtin_amdgcn_mfma_f32_16x16x32_bf16(AfZ[tN][1], bz1v.v, dz, 0, 0, 0);
            f32x4 dq = b2qv[tN];
            dq = __builtin_amdgcn_mfma_f32_16x16x32_bf16(AfQ[tN][0], bq0v.v, dq, 0, 0, 0);
            dq = __builtin_amdgcn_mfma_f32_16x16x32_bf16(AfQ[tN][1], bq1v.v, dq, 0, 0, 0);
            B3z[tN] = pk4(__builtin_elementwise_max(dz, zero4));
            B3q[tN] = pk4(__builtin_elementwise_max(dq, zero4));
        }

        // ---- layer-3: replicated-row A-frags -> P valid on ALL lanes ----
        f32x4 P0 = zero4, P1 = zero4, P2 = zero4, P3 = zero4;
        P0 = __builtin_amdgcn_mfma_f32_16x16x16f16(A3z[0], B3z[0], P0, 0, 0, 0);
        P1 = __builtin_amdgcn_mfma_f32_16x16x16f16(A3z[1], B3z[1], P1, 0, 0, 0);
        P2 = __builtin_amdgcn_mfma_f32_16x16x16f16(A3z[2], B3z[2], P2, 0, 0, 0);
        P3 = __builtin_amdgcn_mfma_f32_16x16x16f16(A3z[3], B3z[3], P3, 0, 0, 0);
        P0 = __builtin_amdgcn_mfma_f32_16x16x16f16(A3q[0], B3q[0], P0, 0, 0, 0);
        P1 = __builtin_amdgcn_mfma_f32_16x16x16f16(A3q[1], B3q[1], P1, 0, 0, 0);
        P2 = __builtin_amdgcn_mfma_f32_16x16x16f16(A3q[2], B3q[2], P2, 0, 0, 0);
        P3 = __builtin_amdgcn_mfma_f32_16x16x16f16(A3q[3], B3q[3], P3, 0, 0, 0);
        f32x4 P = (P0 + P1) + (P2 + P3);

        // ---- epilogue, per-lane (no cross-lane ops) ----
        float z0 = P[0] + zb30, z1 = P[1] + zb31, z2 = P[2] + zb32;
        float qv = P[3] + qb30;

        f32x2 n0 = {nw0, nz0}, n1 = {nw1, nz1}, n2 = {nw2, nz2};
        f32x2 s0 = n0 * SQRTDT, s1 = n1 * SQRTDT, s2 = n2 * SQRTDT;
        f32x2 z0v = {z0, z0}, z1v = {z1, z1}, z2v = {z2, z2};
        f32x2 zd = z2v*s2 + (z1v*s1 + z0v*s0);     // (zdw, zdz)
        float zdw = zd[0], zdz = zd[1];
        float f = 0.5f*qv*qv;
        Yv = Yv - f*DT_ + zdw;
        float r = zdw - zdz;                       // residual: (Y - f*DT) cancels
        acc = fmaf(r, r, acc);
        y = y + qv*DT_ + SIGMA0_*(s0[0] + s1[0] + s2[0]);

        // advance V = A*t + C
#pragma unroll
        for (int m = 0; m < 8; ++m) {
            V1z[m] = V1z[m] + A1z[m] * DT_;
            V1q[m] = V1q[m] + A1q[m] * DT_;
        }
    };

#pragma unroll 1
    for (int i = 0; i < NSTEPS - 4; ++i) {
        __builtin_amdgcn_s_waitcnt(0x0F73);   // vmcnt(3): slot i complete
        fill(i + 4);
        body(i);
    }
    __builtin_amdgcn_s_waitcnt(0x0F70);       // vmcnt(0): drain remaining fills
#pragma unroll 1
    for (int i = NSTEPS - 4; i < NSTEPS; ++i) body(i);

    float dterm = Yv - y*y;
    acc = fmaf(dterm, dterm, acc);

    // q4-replicas hold identical acc -> count q4==0 lanes only
    float val = (q4 == 0) ? acc : 0.0f;
#pragma unroll
    for (int off = 1; off < 64; off <<= 1) val += __shfl_xor(val, off);
    if (lane == 0) atomicAdd(out, val * (1.0f / BATCH));
}

extern "C" void kernel_launch(void* const* d_in, const int* in_sizes, int n_in,
                              void* d_out, int out_size, void* d_ws, size_t ws_size,
                              hipStream_t stream)
{
    zero_out_kernel<<<1, 64, 0, stream>>>((float*)d_out);
    deepbsde_kernel<<<256, 256, 0, stream>>>(
        (const float*)d_in[0],  (const float*)d_in[1],
        (const float*)d_in[2],  (const float*)d_in[3],
        (const float*)d_in[4],  (const float*)d_in[5],
        (const float*)d_in[6],  (const float*)d_in[7],
        (const float*)d_in[8],  (const float*)d_in[9],
        (const float*)d_in[10], (const float*)d_in[11],
        (const float*)d_in[12], (const float*)d_in[13],
        (const float*)d_in[14], (const float*)d_in[15],
        (float*)d_out);
}

// Round 13
// 180.642 us; speedup vs baseline: 1.1432x; 1.0454x over previous
//
#include <hip/hip_runtime.h>
#include <hip/hip_bf16.h>

#define BATCH   16384
#define NSTEPS  100
#define DT_     0.01f
#define SQRTDT  0.1f
#define SIGMA0_ 0.5f

typedef _Float16  f16x2  __attribute__((ext_vector_type(2)));
typedef _Float16  f16x4  __attribute__((ext_vector_type(4)));
typedef _Float16  f16x8  __attribute__((ext_vector_type(8)));
typedef __fp16    h16x2  __attribute__((ext_vector_type(2)));
typedef float     f32x4  __attribute__((ext_vector_type(4)));

typedef const __attribute__((address_space(1))) void* gas_ptr;
typedef __attribute__((address_space(3))) void*       las_ptr;

__global__ void zero_out_kernel(float* out) { if (threadIdx.x == 0) out[0] = 0.0f; }

static __device__ __forceinline__ f16x4 pk4(const f32x4& d) {
    union { h16x2 h[2]; f16x4 v; } c;
    c.h[0] = __builtin_amdgcn_cvt_pkrtz(d[0], d[1]);
    c.h[1] = __builtin_amdgcn_cvt_pkrtz(d[2], d[3]);
    return c.v;
}

// One wave = 16 paths, both MLPs, no barriers, no cross-lane in the loop.
// All pre-MFMA math in packed f16: h1 = v_pk_fma_f16 + v_pk_max_f16, and the
// packed pairs ARE the 16x16x32_f16 B-frag (zero packing cost; was ~400
// VALU instr/step of bf16 RNE packing + frag assembly in R12). Async LDS
// noise ring (depth 4, manual vmcnt(3)), layer-3 MFMA with replicated W3^T
// rows so every lane's P = (z0,z1,z2,q).
__launch_bounds__(256, 1)
__global__ void deepbsde_kernel(
    const float* __restrict__ y0,  const float* __restrict__ Y0,
    const float* __restrict__ zW1, const float* __restrict__ zb1,
    const float* __restrict__ zW2, const float* __restrict__ zb2,
    const float* __restrict__ zW3, const float* __restrict__ zb3,
    const float* __restrict__ qW1, const float* __restrict__ qb1,
    const float* __restrict__ qW2, const float* __restrict__ qb2,
    const float* __restrict__ qW3, const float* __restrict__ qb3,
    const float* __restrict__ dW,  const float* __restrict__ dZ,
    float* __restrict__ out)
{
    __shared__ __align__(16) char ring[4][8][384];   // [wave][slot][16 paths * 24B]

    const int tid  = threadIdx.x;
    const int lane = tid & 63;
    const int w    = tid >> 6;
    const int ln15 = lane & 15, q4 = lane >> 4;
    const int gw   = (blockIdx.x << 2) + w;
    const int pbase = gw << 4;

    // ---- layer-1 consts as f16x2 pairs; pair m covers frag idx (2m,2m+1),
    //      k(idx) = 32*(idx>>3) + 8*q4 + (idx&7) ----
    f16x2 A1z[8], B1z[8], C1z[8], A1q[8], B1q[8], C1q[8];
#pragma unroll
    for (int m = 0; m < 8; ++m) {
        int i0 = 2*m, i1 = 2*m + 1;
        int k0 = 32*(i0 >> 3) + 8*q4 + (i0 & 7);
        int k1 = 32*(i1 >> 3) + 8*q4 + (i1 & 7);
        A1z[m] = (f16x2){(_Float16)zW1[k0],      (_Float16)zW1[k1]};
        B1z[m] = (f16x2){(_Float16)zW1[64 + k0], (_Float16)zW1[64 + k1]};
        C1z[m] = (f16x2){(_Float16)zb1[k0],      (_Float16)zb1[k1]};
        A1q[m] = (f16x2){(_Float16)qW1[k0],      (_Float16)qW1[k1]};
        B1q[m] = (f16x2){(_Float16)qW1[64 + k0], (_Float16)qW1[64 + k1]};
        C1q[m] = (f16x2){(_Float16)qb1[k0],      (_Float16)qb1[k1]};
    }

    // ---- resident W2^T A-frags in f16: A[n=16tN+ln15][k=32f+8q4+j] ----
    f16x8 AfZ[4][2], AfQ[4][2];
#pragma unroll
    for (int tN = 0; tN < 4; ++tN)
#pragma unroll
        for (int f = 0; f < 2; ++f)
#pragma unroll
            for (int j = 0; j < 8; ++j) {
                int k = 32*f + 8*q4 + j, n = 16*tN + ln15;
                AfZ[tN][f][j] = (_Float16)zW2[k*64 + n];
                AfQ[tN][f][j] = (_Float16)qW2[k*64 + n];
            }

    // ---- layer-2 bias along Dt rows: row n = 16tN + 4q4 + r ----
    f32x4 b2zv[4], b2qv[4];
#pragma unroll
    for (int tN = 0; tN < 4; ++tN)
#pragma unroll
        for (int r = 0; r < 4; ++r) {
            b2zv[tN][r] = zb2[16*tN + 4*q4 + r];
            b2qv[tN][r] = qb2[16*tN + 4*q4 + r];
        }

    // ---- layer-3 W3^T A-frags, rows replicated across row-quads ----
    const int c3 = ln15 & 3;
    f16x4 A3z[4], A3q[4];
#pragma unroll
    for (int tN = 0; tN < 4; ++tN)
#pragma unroll
        for (int j = 0; j < 4; ++j) {
            int n = 16*tN + 4*q4 + j;
            A3z[tN][j] = (_Float16)((c3 < 3)  ? zW3[n*3 + c3] : 0.0f);
            A3q[tN][j] = (_Float16)((c3 == 3) ? qW3[n]        : 0.0f);
        }

    float y = y0[0], Yv = Y0[0], t = 0.0f, acc = 0.0f;
    const float zb30 = zb3[0], zb31 = zb3[1], zb32 = zb3[2], qb30 = qb3[0];

    const f16x2 zero2h = {(_Float16)0.0f, (_Float16)0.0f};
    const f32x4 zero4  = {0.0f, 0.0f, 0.0f, 0.0f};

    auto fill = [&](int i) {
        if (lane < 24) {
            const char* g = (lane < 12)
                ? (const char*)dW + ((size_t)i * BATCH + pbase) * 12 + (size_t)lane * 16
                : (const char*)dZ + ((size_t)i * BATCH + pbase) * 12 + (size_t)(lane - 12) * 16;
            __builtin_amdgcn_global_load_lds((gas_ptr)g, (las_ptr)&ring[w][i & 7][0],
                                             16, 0, 0);
        }
    };
    fill(0); fill(1); fill(2); fill(3);

    auto body = [&](int i) {
        const float* sl = (const float*)&ring[w][i & 7][0];
        float nw0 = sl[ln15*3 + 0], nw1 = sl[ln15*3 + 1], nw2 = sl[ln15*3 + 2];
        float nz0 = sl[48 + ln15*3 + 0], nz1 = sl[48 + ln15*3 + 1], nz2 = sl[48 + ln15*3 + 2];

        // ---- h1, packed f16: result pairs ARE the B-frag halves ----
        _Float16 th = (_Float16)t, yh = (_Float16)y;
        const f16x2 tv = {th, th}, yv = {yh, yh};
        union { f16x2 h[4]; f16x8 v; } bz0, bz1, bq0, bq1;
#pragma unroll
        for (int m = 0; m < 8; ++m) {
            f16x2 hz = __builtin_elementwise_max((f16x2)(B1z[m]*yv + (A1z[m]*tv + C1z[m])), zero2h);
            f16x2 hq = __builtin_elementwise_max((f16x2)(B1q[m]*yv + (A1q[m]*tv + C1q[m])), zero2h);
            if (m < 4) { bz0.h[m] = hz;     bq0.h[m] = hq; }
            else       { bz1.h[m - 4] = hz; bq1.h[m - 4] = hq; }
        }

        // ---- layer-2: f16 MFMA, Dt[n][path]; relu -> f16 B-frags ----
        f16x4 B3z[4], B3q[4];
#pragma unroll
        for (int tN = 0; tN < 4; ++tN) {
            f32x4 dz = b2zv[tN];
            dz = __builtin_amdgcn_mfma_f32_16x16x32_f16(AfZ[tN][0], bz0.v, dz, 0, 0, 0);
            dz = __builtin_amdgcn_mfma_f32_16x16x32_f16(AfZ[tN][1], bz1.v, dz, 0, 0, 0);
            f32x4 dq = b2qv[tN];
            dq = __builtin_amdgcn_mfma_f32_16x16x32_f16(AfQ[tN][0], bq0.v, dq, 0, 0, 0);
            dq = __builtin_amdgcn_mfma_f32_16x16x32_f16(AfQ[tN][1], bq1.v, dq, 0, 0, 0);
            B3z[tN] = pk4(__builtin_elementwise_max(dz, zero4));
            B3q[tN] = pk4(__builtin_elementwise_max(dq, zero4));
        }

        // ---- layer-3: replicated-row A-frags -> P valid on ALL lanes ----
        f32x4 P0 = zero4, P1 = zero4, P2 = zero4, P3 = zero4;
        P0 = __builtin_amdgcn_mfma_f32_16x16x16f16(A3z[0], B3z[0], P0, 0, 0, 0);
        P1 = __builtin_amdgcn_mfma_f32_16x16x16f16(A3z[1], B3z[1], P1, 0, 0, 0);
        P2 = __builtin_amdgcn_mfma_f32_16x16x16f16(A3z[2], B3z[2], P2, 0, 0, 0);
        P3 = __builtin_amdgcn_mfma_f32_16x16x16f16(A3z[3], B3z[3], P3, 0, 0, 0);
        P0 = __builtin_amdgcn_mfma_f32_16x16x16f16(A3q[0], B3q[0], P0, 0, 0, 0);
        P1 = __builtin_amdgcn_mfma_f32_16x16x16f16(A3q[1], B3q[1], P1, 0, 0, 0);
        P2 = __builtin_amdgcn_mfma_f32_16x16x16f16(A3q[2], B3q[2], P2, 0, 0, 0);
        P3 = __builtin_amdgcn_mfma_f32_16x16x16f16(A3q[3], B3q[3], P3, 0, 0, 0);
        f32x4 P = (P0 + P1) + (P2 + P3);

        // ---- scalar epilogue, per-lane ----
        float z0 = P[0] + zb30, z1 = P[1] + zb31, z2 = P[2] + zb32;
        float qv = P[3] + qb30;

        float dw0 = SQRTDT*nw0, dw1 = SQRTDT*nw1, dw2 = SQRTDT*nw2;
        float dz0 = SQRTDT*nz0, dz1 = SQRTDT*nz1, dz2 = SQRTDT*nz2;
        float zdw = fmaf(z2, dw2, fmaf(z1, dw1, z0*dw0));
        float zdz = fmaf(z2, dz2, fmaf(z1, dz1, z0*dz0));
        float f = 0.5f*qv*qv;
        Yv = Yv - f*DT_ + zdw;
        float r = zdw - zdz;                       // residual: (Y - f*DT) cancels
        acc = fmaf(r, r, acc);
        y = y + qv*DT_ + SIGMA0_*(dw0 + dw1 + dw2);
        t += DT_;
    };

#pragma unroll 1
    for (int i = 0; i < NSTEPS - 4; ++i) {
        __builtin_amdgcn_s_waitcnt(0x0F73);   // vmcnt(3): slot i complete
        fill(i + 4);
        body(i);
    }
    __builtin_amdgcn_s_waitcnt(0x0F70);       // vmcnt(0): drain remaining fills
#pragma unroll 1
    for (int i = NSTEPS - 4; i < NSTEPS; ++i) body(i);

    float dterm = Yv - y*y;
    acc = fmaf(dterm, dterm, acc);

    // q4-replicas hold identical acc -> count q4==0 lanes only
    float val = (q4 == 0) ? acc : 0.0f;
#pragma unroll
    for (int off = 1; off < 64; off <<= 1) val += __shfl_xor(val, off);
    if (lane == 0) atomicAdd(out, val * (1.0f / BATCH));
}

extern "C" void kernel_launch(void* const* d_in, const int* in_sizes, int n_in,
                              void* d_out, int out_size, void* d_ws, size_t ws_size,
                              hipStream_t stream)
{
    zero_out_kernel<<<1, 64, 0, stream>>>((float*)d_out);
    deepbsde_kernel<<<256, 256, 0, stream>>>(
        (const float*)d_in[0],  (const float*)d_in[1],
        (const float*)d_in[2],  (const float*)d_in[3],
        (const float*)d_in[4],  (const float*)d_in[5],
        (const float*)d_in[6],  (const float*)d_in[7],
        (const float*)d_in[8],  (const float*)d_in[9],
        (const float*)d_in[10], (const float*)d_in[11],
        (const float*)d_in[12], (const float*)d_in[13],
        (const float*)d_in[14], (const float*)d_in[15],
        (float*)d_out);
}